// Round 8
// baseline (153.641 us; speedup 1.0000x reference)
//
#include <hip/hip_runtime.h>
#include <stdint.h>

#define TWF 0.2f
#define NPTS 16384

typedef __attribute__((ext_vector_type(8))) short short8;
typedef __attribute__((ext_vector_type(4))) float floatx4;

__device__ __forceinline__ short f2bf(float f){
  unsigned u = __float_as_uint(f);
  u += 0x7fff + ((u >> 16) & 1);           // round-to-nearest-even
  return (short)(u >> 16);
}
__device__ __forceinline__ float bf2f(short s){
  return __uint_as_float(((unsigned)(unsigned short)s) << 16);
}
// tanh(x) = 1 - 2/(exp2(2*log2e*x)+1); exact at +/-inf
__device__ __forceinline__ float fast_tanh(float x){
  float e = __builtin_amdgcn_exp2f(x * 2.885390082f);
  float r = __builtin_amdgcn_rcpf(e + 1.f);
  return fmaf(-2.f, r, 1.f);
}
// cos(pi*t) via v_cos (revolutions)
__device__ __forceinline__ float cospi_t(float t){
  return __builtin_amdgcn_cosf(t * 0.5f);
}
// packed f32x2 -> bf16x2 (RTNE in HW); low 16 = lo, high 16 = hi
__device__ __forceinline__ unsigned cvt_pk_bf16(float lo, float hi){
  unsigned r;
  asm("v_cvt_pk_bf16_f32 %0, %1, %2" : "=v"(r) : "v"(lo), "v"(hi));
  return r;
}

// ws layout (bytes):
//   [0, 4M)      : bf16-swizzled W1/W2
//   [4M, 8M)     : rec[16][16384] float4 {xn0, xn1, win, pidx-bits}
//                  SEGMENTED: rec[k][chunk*1024 + local], holes between segs
//   [8M, 8M+1K)  : cnt[256] = count of segment (k=s>>4, chunk=s&15)
// No memset needed: every cnt slot is written every launch (no atomics).
#define WS_W      0
#define WS_REC    (4u<<20)
#define WS_CNT    (8u<<20)

struct SMem {
  short lds_h[64 * 256];   // 32 KB, swizzled bf16 h tile, [m][j]
  float s_xn[64 * 2];
  float s_win[64];
  int   s_pidx[64];
  float s_w3[256];
  float s_w0[512];
  int   s_stb[257];        // tile-prefix over 256 segments (persists)
  int   s_c[256];          // per-segment counts (persists)
};                         // 38916 B -> 4 blocks/CU

// ---------------- phase 0: weight conv + out-zero + list build ----------------
// Grid 1024x256. Every block converts its short8 of W1/W2; blocks with
// (bid&3)==0 additionally build ONE (k,chunk) segment's compacted records.
// Slot-deterministic: cnt[seg] is a plain store, rec segment is private.
__global__ __launch_bounds__(256) void fbpinn_p0(
    const float* __restrict__ W1, const float* __restrict__ W2,
    const float* __restrict__ x,  const float* __restrict__ xmins,
    const float* __restrict__ xmaxs, short* __restrict__ dst,
    int* __restrict__ cnt, floatx4* __restrict__ rec, float* __restrict__ out)
{
  __shared__ int s_wrt[16];
  const int bid = blockIdx.x, t = threadIdx.x;
  int gid = bid * 256 + t;                 // 1024x256 = 262144 = 2*16*8*16*64
  {
    int lane = gid & 63; int rest = gid >> 6;
    int jt = rest & 15; rest >>= 4;
    int ks = rest & 7;  rest >>= 3;
    int k  = rest & 15; int mat = rest >> 4;
    const float* W = mat ? W2 : W1;
    int j   = jt * 16 + (lane & 15);
    int kk0 = ks * 32 + (lane >> 4) * 8;
    short8 v;
    #pragma unroll
    for (int jj = 0; jj < 8; jj++)
      v[jj] = f2bf(W[k * 65536 + (kk0 + jj) * 256 + j]);
    *(short8*)(dst + (size_t)gid * 8) = v;
  }
  if (gid < NPTS) out[gid] = 0.f;          // fold memset(out)

  if ((bid & 3) != 0) return;              // list build: 256 blocks, spread
  int L  = bid >> 2;                       // [0,256)
  int k  = L & 15, ch = L >> 4;            // segment (k, chunk)
  int cb = ch * 1024;
  int lane = t & 63, wave = t >> 6;

  float cx  = (xmins[k * 2 + 0] + xmaxs[k * 2 + 0]) * 0.5f;
  float cy  = (xmins[k * 2 + 1] + xmaxs[k * 2 + 1]) * 0.5f;
  float sxi = 1.f / fmaxf((xmaxs[k * 2 + 0] - xmins[k * 2 + 0]) * 0.5f, 1e-9f);
  float syi = 1.f / fmaxf((xmaxs[k * 2 + 1] - xmins[k * 2 + 1]) * 0.5f, 1e-9f);

  float pxr[4], pyr[4], sum[4], wk[4];
  #pragma unroll
  for (int r = 0; r < 4; r++){
    int p = cb + r * 256 + t;
    float2 xy = *(const float2*)&x[p * 2];
    pxr[r] = xy.x; pyr[r] = xy.y; sum[r] = 0.f; wk[r] = 0.f;
  }
  #pragma unroll
  for (int kk = 0; kk < 16; kk++){
    float mnx = xmins[kk * 2 + 0], mny = xmins[kk * 2 + 1];
    float mxx = xmaxs[kk * 2 + 0], mxy = xmaxs[kk * 2 + 1];
    #pragma unroll
    for (int r = 0; r < 4; r++){
      float tlx = fminf(fmaxf((pxr[r] - (mnx - TWF)) * (1.f/(2.f*TWF)), 0.f), 1.f);
      float trx = fminf(fmaxf(((mxx + TWF) - pxr[r]) * (1.f/(2.f*TWF)), 0.f), 1.f);
      float tly = fminf(fmaxf((pyr[r] - (mny - TWF)) * (1.f/(2.f*TWF)), 0.f), 1.f);
      float tr2 = fminf(fmaxf(((mxy + TWF) - pyr[r]) * (1.f/(2.f*TWF)), 0.f), 1.f);
      float wx = 0.25f * (1.f - cospi_t(tlx)) * (1.f - cospi_t(trx));
      float wy = 0.25f * (1.f - cospi_t(tly)) * (1.f - cospi_t(tr2));
      float w  = wx * wy;
      sum[r] += w;
      if (kk == k) wk[r] = w;
    }
  }
  bool act[4]; float wn[4], xa[4], xb[4];
  unsigned long long msk[4]; int wtot[4];
  #pragma unroll
  for (int r = 0; r < 4; r++){
    float inv = 1.f / (sum[r] + 1e-9f);
    act[r] = wk[r] > 0.f;
    wn[r]  = wk[r] * inv;
    xa[r]  = (pxr[r] - cx) * sxi;
    xb[r]  = (pyr[r] - cy) * syi;
    msk[r] = __ballot(act[r]);
    wtot[r] = (int)__popcll(msk[r]);
  }
  if (lane == 0){
    #pragma unroll
    for (int r = 0; r < 4; r++) s_wrt[wave * 4 + r] = wtot[r];
  }
  __syncthreads();
  int wavebase = 0, blocktot = 0;
  #pragma unroll
  for (int w = 0; w < 4; w++){
    int ws_ = s_wrt[w*4+0] + s_wrt[w*4+1] + s_wrt[w*4+2] + s_wrt[w*4+3];
    blocktot += ws_;
    wavebase += (w < wave) ? ws_ : 0;
  }
  if (t == 0) cnt[k * 16 + ch] = blocktot;   // slot write: NO atomic, NO memset
  int rb = 0;
  #pragma unroll
  for (int r = 0; r < 4; r++){
    if (act[r]){
      int pos = wavebase + rb + (int)__popcll(msk[r] & ((1ull << lane) - 1ull));
      int p = cb + r * 256 + t;
      rec[k * NPTS + cb + pos] = (floatx4){xa[r], xb[r], wn[r], __int_as_float(p)};
    }
    rb += s_wrt[wave * 4 + r];
  }
}

// Packed tanh+bf16 writeback: acc[rt][ct] holds D[j'][m]; one cvt_pk pair +
// one 8B ds_write per 4 elements into the chunk-XOR swizzled [m][j] layout.
__device__ __forceinline__ void store_h_packed(
    short* lds_h, const floatx4 (&acc)[4][4], const floatx4 (&bb)[4],
    int wave, int quad, int col){
  #pragma unroll
  for (int rt = 0; rt < 4; rt++){
    const int j0    = (wave * 4 + rt) * 16 + quad * 4;
    const int cbase = j0 >> 3;
    const int off   = j0 & 7;
    #pragma unroll
    for (int ct = 0; ct < 4; ct++){
      const int m = ct * 16 + col;
      float t0 = fast_tanh(acc[rt][ct][0] + bb[rt][0]);
      float t1 = fast_tanh(acc[rt][ct][1] + bb[rt][1]);
      float t2 = fast_tanh(acc[rt][ct][2] + bb[rt][2]);
      float t3 = fast_tanh(acc[rt][ct][3] + bb[rt][3]);
      uint2 v = make_uint2(cvt_pk_bf16(t0, t1), cvt_pk_bf16(t2, t3));
      *(uint2*)&lds_h[m * 256 + ((cbase ^ (m & 7)) << 3) + off] = v;
    }
  }
}

// ---------------- phase 1: tiled MLP over compacted segments ----------------
__global__ __launch_bounds__(256, 4) void fbpinn_p1(
    const float* __restrict__ W0, const float* __restrict__ b0,
    const float* __restrict__ b1, const float* __restrict__ b2,
    const float* __restrict__ W3, const float* __restrict__ b3,
    const short* __restrict__ wsw, const int* __restrict__ cnt,
    const floatx4* __restrict__ rec, float* __restrict__ out)
{
  __shared__ SMem sm;
  const int bid  = blockIdx.x, t = threadIdx.x;
  const int lane = t & 63;
  const int wave = t >> 6;
  const int col  = lane & 15;
  const int quad = lane >> 4;

  // tile map: parallel scan of per-segment tile counts (scratch in lds_h)
  int* s_scan = (int*)sm.lds_h;
  if (t < 256){ int c = cnt[t]; sm.s_c[t] = c; s_scan[t] = (c + 63) >> 6; }
  __syncthreads();
  for (int off = 1; off < 256; off <<= 1){
    int v = (t >= off) ? s_scan[t - off] : 0;
    __syncthreads();
    s_scan[t] += v;
    __syncthreads();
  }
  if (t < 256) sm.s_stb[t + 1] = s_scan[t];
  if (t == 0)  sm.s_stb[0] = 0;
  __syncthreads();
  const int total = sm.s_stb[256];

  // XCD-chunked tile mapping: segments are k-major; contiguous chunk per XCD
  const int xcd    = bid & 7;
  const int nb     = gridDim.x >> 3;
  const int chunkT = (total + 7) >> 3;

  for (int idx = bid >> 3; idx < chunkT; idx += nb){
    const int tile = xcd * chunkT + idx;
    if (tile >= total) break;
    // segment lookup: binary search in LDS prefix (uniform -> broadcast)
    int lo = 0, hi = 256;
    while (hi - lo > 1){
      int mid = (lo + hi) >> 1;
      if (tile >= sm.s_stb[mid]) lo = mid; else hi = mid;
    }
    const int seg = lo, k = seg >> 4, ch = seg & 15;
    const int c     = sm.s_c[seg];
    const int lbase = (tile - sm.s_stb[seg]) * 64;
    const floatx4* rbase = rec + k * NPTS + ch * 1024;

    __syncthreads();   // prev tile's layer-3 reads done before overwrite

    // ---- stage: one coalesced 16B record per point ----
    sm.s_w3[t] = W3[k * 256 + t];
    sm.s_w0[t] = W0[k * 512 + t];
    sm.s_w0[256 + t] = W0[k * 512 + 256 + t];
    if (t < 64){
      int li = lbase + t;
      bool valid = li < c;
      floatx4 rcd = rbase[valid ? li : 0];
      sm.s_pidx[t] = __float_as_int(rcd[3]);
      sm.s_win[t]  = valid ? rcd[2] : 0.f;
      sm.s_xn[t * 2 + 0] = rcd[0];
      sm.s_xn[t * 2 + 1] = rcd[1];
    }
    __syncthreads();

    // ---- layer 0 (D=2 -> 256): D[j'][m] = W0^T * xn^T ----
    {
      short8 wfr[4], xfr[4];
      #pragma unroll
      for (int rt = 0; rt < 4; rt++){
        int j = (wave * 4 + rt) * 16 + col;
        short8 a;
        #pragma unroll
        for (int i = 0; i < 8; i++) a[i] = 0;
        a[0] = (quad == 0) ? f2bf(sm.s_w0[j])       : (short)0;
        a[1] = (quad == 0) ? f2bf(sm.s_w0[256 + j]) : (short)0;
        wfr[rt] = a;
      }
      #pragma unroll
      for (int ct = 0; ct < 4; ct++){
        int m = ct * 16 + col;
        short8 b;
        #pragma unroll
        for (int i = 0; i < 8; i++) b[i] = 0;
        b[0] = (quad == 0) ? f2bf(sm.s_xn[m * 2 + 0]) : (short)0;
        b[1] = (quad == 0) ? f2bf(sm.s_xn[m * 2 + 1]) : (short)0;
        xfr[ct] = b;
      }
      floatx4 bb[4];
      #pragma unroll
      for (int rt = 0; rt < 4; rt++)
        bb[rt] = *(const floatx4*)&b0[k * 256 + (wave * 4 + rt) * 16 + quad * 4];
      floatx4 acc[4][4];
      #pragma unroll
      for (int a = 0; a < 4; a++)
        #pragma unroll
        for (int b = 0; b < 4; b++)
          acc[a][b] = (floatx4){0.f, 0.f, 0.f, 0.f};
      #pragma unroll
      for (int rt = 0; rt < 4; rt++)
        #pragma unroll
        for (int ct = 0; ct < 4; ct++)
          acc[rt][ct] = __builtin_amdgcn_mfma_f32_16x16x32_bf16(wfr[rt], xfr[ct], acc[rt][ct], 0, 0, 0);
      store_h_packed(sm.lds_h, acc, bb, wave, quad, col);
      __syncthreads();
    }

    // ---- layers 1,2: D[j'][m] = W^T * h^T ----
    #pragma unroll 1
    for (int layer = 0; layer < 2; layer++){
      const short8* wb = (const short8*)(wsw + (size_t)layer * 1048576)
                         + ((size_t)(k * 8) * 16 + wave * 4) * 64 + lane;
      const float*  bp = layer ? b2 : b1;
      floatx4 bb[4];
      #pragma unroll
      for (int rt = 0; rt < 4; rt++)
        bb[rt] = *(const floatx4*)&bp[k * 256 + (wave * 4 + rt) * 16 + quad * 4];
      floatx4 acc[4][4];
      #pragma unroll
      for (int a = 0; a < 4; a++)
        #pragma unroll
        for (int b = 0; b < 4; b++)
          acc[a][b] = (floatx4){0.f, 0.f, 0.f, 0.f};

      short8 wcur[4];
      #pragma unroll
      for (int rt = 0; rt < 4; rt++) wcur[rt] = wb[rt * 64];

      #pragma unroll
      for (int ks = 0; ks < 8; ks++){
        short8 wnxt[4];
        if (ks < 7){
          #pragma unroll
          for (int rt = 0; rt < 4; rt++)
            wnxt[rt] = wb[(ks + 1) * 1024 + rt * 64];
        }
        short8 hfr[4];
        #pragma unroll
        for (int ct = 0; ct < 4; ct++){
          int m   = ct * 16 + col;
          int pos = (ks * 4 + quad) ^ (m & 7);
          hfr[ct] = *(const short8*)&sm.lds_h[m * 256 + pos * 8];
        }
        #pragma unroll
        for (int rt = 0; rt < 4; rt++)
          #pragma unroll
          for (int ct = 0; ct < 4; ct++)
            acc[rt][ct] = __builtin_amdgcn_mfma_f32_16x16x32_bf16(wcur[rt], hfr[ct], acc[rt][ct], 0, 0, 0);
        if (ks < 7){
          #pragma unroll
          for (int rt = 0; rt < 4; rt++) wcur[rt] = wnxt[rt];
        }
      }
      __syncthreads();

      store_h_packed(sm.lds_h, acc, bb, wave, quad, col);
      __syncthreads();
    }

    // ---- layer 3 (256 -> 1) + window-weighted scatter ----
    {
      int m = t >> 2, q = t & 3;
      float dot = 0.f;
      #pragma unroll
      for (int cc = 0; cc < 8; cc++){
        int ci  = q * 8 + cc;
        int pos = ci ^ (m & 7);
        short8 hv = *(const short8*)&sm.lds_h[m * 256 + pos * 8];
        #pragma unroll
        for (int jj = 0; jj < 8; jj++)
          dot = fmaf(bf2f(hv[jj]), sm.s_w3[ci * 8 + jj], dot);
      }
      dot += __shfl_xor(dot, 1);
      dot += __shfl_xor(dot, 2);
      if (q == 0 && sm.s_win[m] != 0.f)
        atomicAdd(&out[sm.s_pidx[m]], sm.s_win[m] * (dot + b3[k]));
    }
  }
}

extern "C" void kernel_launch(void* const* d_in, const int* in_sizes, int n_in,
                              void* d_out, int out_size, void* d_ws, size_t ws_size,
                              hipStream_t stream){
  const float* x     = (const float*)d_in[0];
  const float* W0    = (const float*)d_in[1];
  const float* b0    = (const float*)d_in[2];
  const float* W1    = (const float*)d_in[3];
  const float* b1    = (const float*)d_in[4];
  const float* W2    = (const float*)d_in[5];
  const float* b2    = (const float*)d_in[6];
  const float* W3    = (const float*)d_in[7];
  const float* b3    = (const float*)d_in[8];
  const float* xmins = (const float*)d_in[9];
  const float* xmaxs = (const float*)d_in[10];
  float* out = (float*)d_out;

  char* ws = (char*)d_ws;                     // needs ~8.01 MB
  short*   wsw  = (short*)  (ws + WS_W);
  floatx4* rec  = (floatx4*)(ws + WS_REC);
  int*     cnt  = (int*)    (ws + WS_CNT);

  // Two plain dispatches (graph-capture-safe; NO cooperative launch, NO
  // memset, NO atomics): p0 = weight conv + out-zero + deterministic
  // per-segment list build; p1 = tiled MFMA MLP.
  fbpinn_p0<<<1024, 256, 0, stream>>>(W1, W2, x, xmins, xmaxs,
                                      wsw, cnt, rec, out);
  fbpinn_p1<<<1024, 256, 0, stream>>>(W0, b0, b1, b2, W3, b3,
                                      wsw, cnt, rec, out);
}